// Round 10
// baseline (273.424 us; speedup 1.0000x reference)
//
#include <hip/hip_runtime.h>
#include <hip/hip_bf16.h>
#include <math.h>
#include <stdint.h>

// MHA pipeline: split_x + transpose weights (hi/lo bf16) + rope tables ->
// split QKV GEMM (3-term bf16 MFMA) -> rope+scatter (Q pre-scaled log2e/8) ->
// flash attention (4 waves x 16 q-rows, 1024 blocks = 12 waves/CU, K dbuf
// gload_lds, V reg-staged->LDS, in-register P, bh-fast grid) -> out GEMM.

typedef __bf16 bf16;
typedef __bf16 bf16x8 __attribute__((ext_vector_type(8)));
typedef __bf16 bf16x4 __attribute__((ext_vector_type(4)));
typedef float f32x4 __attribute__((ext_vector_type(4)));

#define AS1 __attribute__((address_space(1)))
#define AS3 __attribute__((address_space(3)))

__device__ __forceinline__ void gload_lds16(const void* g, void* l) {
  __builtin_amdgcn_global_load_lds((const AS1 void*)g, (AS3 void*)l, 16, 0, 0);
}

__device__ __forceinline__ f32x4 mfma16(bf16x8 a, bf16x8 b, f32x4 c) {
  return __builtin_amdgcn_mfma_f32_16x16x32_bf16(a, b, c, 0, 0, 0);
}

#define S_LEN 2048
#define QSCALE 0.1803368801111144f  /* log2(e)/8 */

// ---------------- prep kernels ----------------

__global__ void k_split_x(const float* __restrict__ x, bf16* __restrict__ xh,
                          bf16* __restrict__ xl) {
  int i = blockIdx.x * 256 + threadIdx.x;
  float4 v = ((const float4*)x)[i];
  float vv[4] = {v.x, v.y, v.z, v.w};
  bf16x4 h, l;
#pragma unroll
  for (int j = 0; j < 4; j++) {
    bf16 hb = (bf16)vv[j];
    h[j] = hb;
    l[j] = (bf16)(vv[j] - (float)hb);
  }
  ((bf16x4*)xh)[i] = h;
  ((bf16x4*)xl)[i] = l;
}

__global__ void k_wt_qkv(const float* __restrict__ w, bf16* __restrict__ bth,
                         bf16* __restrict__ btl) {
  __shared__ float t[32][33];
  int n0 = blockIdx.x * 32, k0 = blockIdx.y * 32;
  int tx = threadIdx.x & 31, ty = threadIdx.x >> 5;
#pragma unroll
  for (int i = 0; i < 4; i++)
    t[ty + 8 * i][tx] = w[(size_t)(k0 + ty + 8 * i) * 3072 + n0 + tx];
  __syncthreads();
#pragma unroll
  for (int i = 0; i < 4; i++) {
    int r = ty + 8 * i;
    float v = t[tx][r];
    size_t o = (size_t)(n0 + r) * 1024 + k0 + tx;
    bf16 hb = (bf16)v;
    bth[o] = hb;
    btl[o] = (bf16)(v - (float)hb);
  }
}

__global__ void k_wt_out(const float* __restrict__ w, bf16* __restrict__ bt) {
  __shared__ float t[32][33];
  int n0 = blockIdx.x * 32, k0 = blockIdx.y * 32;
  int tx = threadIdx.x & 31, ty = threadIdx.x >> 5;
#pragma unroll
  for (int i = 0; i < 4; i++)
    t[ty + 8 * i][tx] = w[(size_t)(k0 + ty + 8 * i) * 1024 + n0 + tx];
  __syncthreads();
#pragma unroll
  for (int i = 0; i < 4; i++) {
    int r = ty + 8 * i;
    bt[(size_t)(n0 + r) * 1024 + k0 + tx] = (bf16)t[tx][r];
  }
}

// fp32 trig: arg error <= 2048*2^-24 ~ 1.2e-4 rad, negligible vs bf16
// rounding (4e-3) downstream. f64 pow/cos were software-emulated and slow.
__global__ void k_rope_tables(float* __restrict__ ct, float* __restrict__ st) {
  int i = blockIdx.x * 256 + threadIdx.x;   // 65536
  int s = i >> 5, j = i & 31;
  float invf = powf(10000.0f, -(float)j / 32.0f);
  float a = (float)s * invf;
  ct[i] = cosf(a);
  st[i] = sinf(a);
}

// ---------------- QKV GEMM ----------------
__global__ __launch_bounds__(256, 2) void k_gemm_qkv(
    const bf16* __restrict__ Ah, const bf16* __restrict__ Al,
    const bf16* __restrict__ Bh, const bf16* __restrict__ Bl,
    bf16* __restrict__ C) {
  const int K = 1024, N = 3072;
  __shared__ __align__(16) bf16 sAh[128 * 32];
  __shared__ __align__(16) bf16 sAl[128 * 32];
  __shared__ __align__(16) bf16 sBh[128 * 32];
  __shared__ __align__(16) bf16 sBl[128 * 32];
  int tid = threadIdx.x, lane = tid & 63, wid = tid >> 6;
  int m0 = blockIdx.x * 128, n0 = blockIdx.y * 128;
  int wm = wid >> 1, wn = wid & 1;

  f32x4 acc[4][4];
#pragma unroll
  for (int a = 0; a < 4; a++)
#pragma unroll
    for (int b = 0; b < 4; b++) acc[a][b] = (f32x4){0.f, 0.f, 0.f, 0.f};

  for (int k0 = 0; k0 < K; k0 += 32) {
#pragma unroll
    for (int p = 0; p < 2; p++) {
      int slot = p * 256 + tid;
      int row = slot >> 2, c16 = slot & 3;
      int cs = c16 ^ ((row >> 1) & 3);
      int ldsoff = (p * 256 + wid * 64) * 16;
      size_t ga = (size_t)(m0 + row) * K + k0 + cs * 8;
      size_t gb = (size_t)(n0 + row) * K + k0 + cs * 8;
      gload_lds16(Ah + ga, (char*)sAh + ldsoff);
      gload_lds16(Al + ga, (char*)sAl + ldsoff);
      gload_lds16(Bh + gb, (char*)sBh + ldsoff);
      gload_lds16(Bl + gb, (char*)sBl + ldsoff);
    }
    __syncthreads();

    bf16x8 fah[4], fal[4], fbh[4], fbl[4];
#pragma unroll
    for (int mf = 0; mf < 4; mf++) {
      int row = wm * 64 + mf * 16 + (lane & 15);
      int c16 = (lane >> 4) ^ ((row >> 1) & 3);
      int off = row * 64 + c16 * 16;
      fah[mf] = *(const bf16x8*)((const char*)sAh + off);
      fal[mf] = *(const bf16x8*)((const char*)sAl + off);
    }
#pragma unroll
    for (int nf = 0; nf < 4; nf++) {
      int row = wn * 64 + nf * 16 + (lane & 15);
      int c16 = (lane >> 4) ^ ((row >> 1) & 3);
      int off = row * 64 + c16 * 16;
      fbh[nf] = *(const bf16x8*)((const char*)sBh + off);
      fbl[nf] = *(const bf16x8*)((const char*)sBl + off);
    }
#pragma unroll
    for (int mf = 0; mf < 4; mf++)
#pragma unroll
      for (int nf = 0; nf < 4; nf++) {
        acc[mf][nf] = mfma16(fah[mf], fbh[nf], acc[mf][nf]);
        acc[mf][nf] = mfma16(fah[mf], fbl[nf], acc[mf][nf]);
        acc[mf][nf] = mfma16(fal[mf], fbh[nf], acc[mf][nf]);
      }
    __syncthreads();
  }

#pragma unroll
  for (int mf = 0; mf < 4; mf++)
#pragma unroll
    for (int nf = 0; nf < 4; nf++)
#pragma unroll
      for (int r = 0; r < 4; r++) {
        int row = m0 + wm * 64 + mf * 16 + (lane >> 4) * 4 + r;
        int col = n0 + wn * 64 + nf * 16 + (lane & 15);
        C[(size_t)row * N + col] = (bf16)acc[mf][nf][r];
      }
}

// ---------------- RoPE + scatter (Q pre-scaled by log2e/8) ----------------
__global__ void k_rope_scatter(const bf16* __restrict__ QKV,
                               const float* __restrict__ ct,
                               const float* __restrict__ st,
                               bf16* __restrict__ Q, bf16* __restrict__ Kb,
                               bf16* __restrict__ Vt) {
  __shared__ __align__(16) bf16 vt[64 * 64];
  int sblk = blockIdx.x, bh = blockIdx.y;
  int b = bh >> 4, h = bh & 15;
  int tid = threadIdx.x;
  int r = tid >> 2, c = tid & 3;
  int s = sblk * 64 + r;
  size_t rowbase = ((size_t)(b * S_LEN + s)) * 3072 + h * 192;

  bf16x8 qlo = *(const bf16x8*)(QKV + rowbase + c * 8);
  bf16x8 qhi = *(const bf16x8*)(QKV + rowbase + c * 8 + 32);
  bf16x8 klo = *(const bf16x8*)(QKV + rowbase + 64 + c * 8);
  bf16x8 khi = *(const bf16x8*)(QKV + rowbase + 64 + c * 8 + 32);
  bf16x8 vlo = *(const bf16x8*)(QKV + rowbase + 128 + c * 8);
  bf16x8 vhi = *(const bf16x8*)(QKV + rowbase + 128 + c * 8 + 32);

  bf16x8 qol, qoh, kol, koh;
#pragma unroll
  for (int j = 0; j < 8; j++) {
    float cs = ct[s * 32 + c * 8 + j], sn = st[s * 32 + c * 8 + j];
    float q1 = (float)qlo[j], q2 = (float)qhi[j];
    qol[j] = (bf16)((q1 * cs - q2 * sn) * QSCALE);
    qoh[j] = (bf16)((q2 * cs + q1 * sn) * QSCALE);
    float k1 = (float)klo[j], k2 = (float)khi[j];
    kol[j] = (bf16)(k1 * cs - k2 * sn);
    koh[j] = (bf16)(k2 * cs + k1 * sn);
  }
  size_t qb = ((size_t)bh * S_LEN + s) * 64 + c * 8;
  *(bf16x8*)(Q + qb) = qol;
  *(bf16x8*)(Q + qb + 32) = qoh;
  *(bf16x8*)(Kb + qb) = kol;
  *(bf16x8*)(Kb + qb + 32) = koh;

#pragma unroll
  for (int j = 0; j < 8; j++) {
    vt[(c * 8 + j) * 64 + r] = vlo[j];
    vt[(c * 8 + 32 + j) * 64 + r] = vhi[j];
  }
  __syncthreads();
  int d = tid >> 2, cc = tid & 3;
  size_t vb = ((size_t)bh * 64 + d) * S_LEN + sblk * 64 + cc * 16;
  *(bf16x8*)(Vt + vb) = *(const bf16x8*)(vt + d * 64 + cc * 16);
  *(bf16x8*)(Vt + vb + 8) = *(const bf16x8*)(vt + d * 64 + cc * 16 + 8);
}

// ---------------- Flash attention ----------------
// 256 thr = 4 waves; wave w owns 16 q-rows (qt*64 + w*16 + q).
// Grid dim3(32 bh fast, 32 qt) = 1024 blocks -> 3 blocks/CU (LDS 48KB cap)
// = 12 waves/CU (R9 was 512 blocks = 2/CU = 8 waves/CU, VALU chains
// exposed). All qt of a head on one XCD -> K/V L2-hot (R7/R8 proven).
// K tiles: double-buffered LDS via global_load_lds, prefetch at kt start,
// drained at post-PV barrier. V tile: single LDS buffer, reg-staged (T14):
// global->reg at kt start (hidden), reg->ds_write after barrier A.
// Swapped-operand S^T = mfma(K,Q) (exp2 domain), in-register P with k-slot
// permutation tau(g,j)=16*(j>>2)+4g+(j&3) applied to BOTH PV operands.
// Mask row-check hoisted out of kt loop (wave scans full row once).
// lb(256,2): allocator never forced to spill (R6/R7: cap 128 -> 264MB scratch).
__global__ __launch_bounds__(256, 2) void k_attn(
    const bf16* __restrict__ Q, const bf16* __restrict__ Kb,
    const bf16* __restrict__ Vt, const int* __restrict__ mask,
    bf16* __restrict__ Ctx) {
  __shared__ __align__(16) char sK[2][16384];
  __shared__ __align__(16) char sV[16384];
  int tid = threadIdx.x, lane = tid & 63, w = tid >> 6;
  int g = lane >> 4, q = lane & 15;
  int bh = blockIdx.x, qt = blockIdx.y;   // bh fast-varying: XCD/L2 locality
  int b = bh >> 4, h = bh & 15;
  int qrow = qt * 64 + w * 16 + q;

  // Q as B-operand (pre-scaled by log2e/8 upstream)
  bf16x8 bQ[2];
#pragma unroll
  for (int ks = 0; ks < 2; ks++)
    bQ[ks] = *(const bf16x8*)(Q + ((size_t)bh * S_LEN + qrow) * 64 + ks * 32 + g * 8);

  f32x4 O[4];
#pragma unroll
  for (int nd = 0; nd < 4; nd++) O[nd] = (f32x4){0.f, 0.f, 0.f, 0.f};
  float mrow = -3e38f, lrow = 0.f;

  // hoisted whole-row mask check: lane covers mask[lane*32 .. lane*32+31]
  bool rowall;
  {
    int acc = -1;
    const int4* mr = (const int4*)(mask + (size_t)b * S_LEN) + lane * 8;
#pragma unroll
    for (int p = 0; p < 8; p++) {
      int4 m4 = mr[p];
      acc &= m4.x & m4.y & m4.z & m4.w;
    }
    rowall = __all(acc != 0);
  }

  const bf16* kbase = Kb + (size_t)bh * S_LEN * 64;
  const bf16* vbase = Vt + (size_t)bh * 64 * S_LEN;

  // prologue: K[0] -> sK[0] (gload_lds), V[0] -> regs -> sV
#pragma unroll
  for (int p = 0; p < 4; p++) {
    int slot = p * 256 + tid;
    int row = slot >> 3, c16 = slot & 7;
    int cs = c16 ^ (row & 7);
    gload_lds16(kbase + (size_t)row * 64 + cs * 8, sK[0] + (p * 256 + w * 64) * 16);
  }
  bf16x8 vst[4];
#pragma unroll
  for (int p = 0; p < 4; p++) {
    int slot = p * 256 + tid;
    int row = slot >> 4, c16 = slot & 15;
    int cs = c16 ^ (row & 7);
    vst[p] = *(const bf16x8*)(vbase + (size_t)row * S_LEN + cs * 8);
  }
#pragma unroll
  for (int p = 0; p < 4; p++)
    *(bf16x8*)(sV + (p * 256 + tid) * 16) = vst[p];
  __syncthreads();

  int db = 0;
  for (int kt = 0; kt < 16; kt++) {
    int k0 = kt * 128;
    if (kt < 15) {
      // issue next K tile -> LDS (async) and next V tile -> regs; both
      // consumed only after the post-PV barrier: latency fully hidden.
#pragma unroll
      for (int p = 0; p < 4; p++) {
        int slot = p * 256 + tid;
        int row = slot >> 3, c16 = slot & 7;
        int cs = c16 ^ (row & 7);
        gload_lds16(kbase + (size_t)((kt + 1) * 128 + row) * 64 + cs * 8,
                    sK[db ^ 1] + (p * 256 + w * 64) * 16);
      }
#pragma unroll
      for (int p = 0; p < 4; p++) {
        int slot = p * 256 + tid;
        int row = slot >> 4, c16 = slot & 15;
        int cs = c16 ^ (row & 7);
        vst[p] = *(const bf16x8*)(vbase + (size_t)row * S_LEN + (kt + 1) * 128 + cs * 8);
      }
    }
    const char* kl = sK[db];

    // S^T = K Q^T  (lane holds S^T[key = kf*16 + 4g + r][qrow])
    f32x4 sfr[8];
#pragma unroll
    for (int kf = 0; kf < 8; kf++) sfr[kf] = (f32x4){0.f, 0.f, 0.f, 0.f};
#pragma unroll
    for (int kf = 0; kf < 8; kf++) {
#pragma unroll
      for (int ks = 0; ks < 2; ks++) {
        int row = kf * 16 + q;
        int c16 = (ks * 4 + g) ^ (row & 7);
        bf16x8 ak = *(const bf16x8*)(kl + row * 128 + c16 * 16);
        sfr[kf] = mfma16(ak, bQ[ks], sfr[kf]);
      }
    }
    // mask slow path (uniform branch; bench mask is all ones)
    if (!rowall) {
#pragma unroll
      for (int kf = 0; kf < 8; kf++) {
        int4 m4 = *(const int4*)(mask + b * S_LEN + k0 + kf * 16 + g * 4);
        int mm[4] = {m4.x, m4.y, m4.z, m4.w};
#pragma unroll
        for (int r = 0; r < 4; r++)
          if (mm[r] == 0) sfr[kf][r] = -1e30f;
      }
    }
    // online softmax in exp2 domain, defer-max THR=8
    {
      float mx = -3e38f;
#pragma unroll
      for (int kf = 0; kf < 8; kf++)
#pragma unroll
        for (int r = 0; r < 4; r++) mx = fmaxf(mx, sfr[kf][r]);
      mx = fmaxf(mx, __shfl_xor(mx, 16, 64));
      mx = fmaxf(mx, __shfl_xor(mx, 32, 64));
      if (__any(mx > mrow + 8.0f)) {
        float mnew = fmaxf(mrow, mx);
        float al = exp2f(mrow - mnew);
        mrow = mnew;
        lrow *= al;
#pragma unroll
        for (int nd = 0; nd < 4; nd++)
#pragma unroll
          for (int r = 0; r < 4; r++) O[nd][r] *= al;
      }
      float ps = 0.f;
#pragma unroll
      for (int kf = 0; kf < 8; kf++)
#pragma unroll
        for (int r = 0; r < 4; r++) {
          float p0 = exp2f(sfr[kf][r] - mrow);
          sfr[kf][r] = p0;
          ps += p0;
        }
      ps += __shfl_xor(ps, 16, 64);
      ps += __shfl_xor(ps, 32, 64);
      lrow += ps;
    }

    // PV: P^T from own registers; V from sV with MATCHING tau permutation:
    // av[j] -> key = ks*32 + 16*(j>>2) + g*4 + (j&3)  (two ds_read_b64)
#pragma unroll
    for (int ks = 0; ks < 4; ks++) {
      bf16x8 pb;
#pragma unroll
      for (int j = 0; j < 8; j++)
        pb[j] = (bf16)sfr[2 * ks + (j >> 2)][j & 3];
#pragma unroll
      for (int nd = 0; nd < 4; nd++) {
        int row = nd * 16 + q;
        int u1 = (ks * 4 + (g >> 1)) ^ (row & 7);
        int u2 = (ks * 4 + (g >> 1) + 2) ^ (row & 7);
        const char* vr = sV + row * 256 + ((g & 1) << 3);
        bf16x4 v0 = *(const bf16x4*)(vr + (u1 << 4));
        bf16x4 v1 = *(const bf16x4*)(vr + (u2 << 4));
        bf16x8 av;
#pragma unroll
        for (int j = 0; j < 4; j++) { av[j] = v0[j]; av[4 + j] = v1[j]; }
        O[nd] = mfma16(av, pb, O[nd]);
      }
    }
    __syncthreads();   // A: PV done everywhere; drains K prefetch + V reg loads
    if (kt < 15) {
#pragma unroll
      for (int p = 0; p < 4; p++)
        *(bf16x8*)(sV + (p * 256 + tid) * 16) = vst[p];
    }
    __syncthreads();   // B: sV[kt+1] visible to all waves
    db ^= 1;
  }

  float inv = 1.f / lrow;
#pragma unroll
  for (int nd = 0; nd < 4; nd++) {
    bf16x4 o4;
#pragma unroll
    for (int r = 0; r < 4; r++) o4[r] = (bf16)(O[nd][r] * inv);
    *(bf16x4*)(Ctx + ((size_t)b * S_LEN + qrow) * 1024 + h * 64 + nd * 16 + g * 4) = o4;
  }
}

// ---------------- out GEMM ----------------
__global__ __launch_bounds__(256, 2) void k_gemm_out(
    const bf16* __restrict__ A, const bf16* __restrict__ Bt,
    float* __restrict__ C) {
  const int K = 1024, N = 1024;
  __shared__ __align__(16) bf16 sA[128 * 32];
  __shared__ __align__(16) bf16 sB[128 * 32];
  int tid = threadIdx.x, lane = tid & 63, wid = tid >> 6;
  int m0 = blockIdx.x * 128, n0 = blockIdx.y * 128;
  int wm = wid >> 1, wn = wid & 1;

  f32x4 acc[4][4];
#pragma unroll
  for (int a = 0; a < 4; a++)
#pragma unroll
    for (int b = 0; b < 4; b++) acc[a][b] = (f32x4){0.f, 0.f, 0.f, 0.f};

  for (int k0 = 0; k0 < K; k0 += 32) {
#pragma unroll
    for (int p = 0; p < 2; p++) {
      int slot = p * 256 + tid;
      int row = slot >> 2, c16 = slot & 3;
      int cs = c16 ^ ((row >> 1) & 3);
      int ldsoff = (p * 256 + wid * 64) * 16;
      gload_lds16(A + (size_t)(m0 + row) * K + k0 + cs * 8, (char*)sA + ldsoff);
      gload_lds16(Bt + (size_t)(n0 + row) * K + k0 + cs * 8, (char*)sB + ldsoff);
    }
    __syncthreads();
    bf16x8 fa[4], fb[4];
#pragma unroll
    for (int mf = 0; mf < 4; mf++) {
      int row = wm * 64 + mf * 16 + (lane & 15);
      int c16 = (lane >> 4) ^ ((row >> 1) & 3);
      fa[mf] = *(const bf16x8*)((const char*)sA + row * 64 + c16 * 16);
    }
#pragma unroll
    for (int nf = 0; nf < 4; nf++) {
      int row = wn * 64 + nf * 16 + (lane & 15);
      int c16 = (lane >> 4) ^ ((row >> 1) & 3);
      fb[nf] = *(const bf16x8*)((const char*)sB + row * 64 + c16 * 16);
    }
#pragma unroll
    for (int mf = 0; mf < 4; mf++)
#pragma unroll
      for (int nf = 0; nf < 4; nf++)
        acc[mf][nf] = mfma16(fa[mf], fb[nf], acc[mf][nf]);
    __syncthreads();
  }
#pragma unroll
  for (int mf = 0; mf < 4; mf++)
#pragma unroll
    for (int nf = 0; nf < 4; nf++)
#pragma unroll
      for (int r = 0; r < 4; r++) {
        int row = m0 + wm * 64 + mf * 16 + (lane >> 4) * 4 + r;
        int col = n0 + wn * 64 + nf * 16 + (lane & 15);
        C[(size_t)row * N + col] = acc[mf][nf][r];
      }
}

// ---------------- launch ----------------
extern "C" void kernel_launch(void* const* d_in, const int* in_sizes, int n_in,
                              void* d_out, int out_size, void* d_ws, size_t ws_size,
                              hipStream_t stream) {
  const float* x = (const float*)d_in[0];
  const int* mask = (const int*)d_in[1];
  const float* wqkv = (const float*)d_in[2];
  const float* wout = (const float*)d_in[3];
  float* out = (float*)d_out;
  char* ws = (char*)d_ws;

  bf16* Xh  = (bf16*)(ws + 0);
  bf16* Xl  = (bf16*)(ws + 8388608);
  bf16* Wqh = (bf16*)(ws + 16777216);
  bf16* Wql = (bf16*)(ws + 23068672);
  bf16* Wo  = (bf16*)(ws + 29360128);
  bf16* QKV = (bf16*)(ws + 31457280);
  bf16* Qb  = (bf16*)(ws + 56623104);
  bf16* Kb  = (bf16*)(ws + 65011712);
  bf16* Vt  = (bf16*)(ws + 73400320);
  bf16* Ctx = (bf16*)(ws + 81788928);
  float* ct = (float*)(ws + 90177536);
  float* st = (float*)(ws + 90439680);

  k_split_x<<<4096, 256, 0, stream>>>(x, Xh, Xl);
  k_wt_qkv<<<dim3(96, 32), 256, 0, stream>>>(wqkv, Wqh, Wql);
  k_wt_out<<<dim3(32, 32), 256, 0, stream>>>(wout, Wo);
  k_rope_tables<<<256, 256, 0, stream>>>(ct, st);
  k_gemm_qkv<<<dim3(32, 24), 256, 0, stream>>>(Xh, Xl, Wqh, Wql, QKV);
  k_rope_scatter<<<dim3(32, 32), 256, 0, stream>>>(QKV, ct, st, Qb, Kb, Vt);
  k_attn<<<dim3(32, 32), 256, 0, stream>>>(Qb, Kb, Vt, mask, Ctx);
  k_gemm_out<<<dim3(32, 8), 256, 0, stream>>>(Ctx, Wo, out);
}

// Round 11
// 259.504 us; speedup vs baseline: 1.0536x; 1.0536x over previous
//
#include <hip/hip_runtime.h>
#include <hip/hip_bf16.h>
#include <math.h>
#include <stdint.h>

// MHA pipeline: split_x + transpose weights (hi/lo bf16) + rope tables ->
// split QKV GEMM (3-term bf16 MFMA) -> rope+scatter (Q pre-scaled log2e/8) ->
// flash attention (4 waves x 32 q-rows, K+V both dbuf in LDS, ONE barrier
// per kt, hoisted addressing, bh-fast grid) -> out GEMM.

typedef __bf16 bf16;
typedef __bf16 bf16x8 __attribute__((ext_vector_type(8)));
typedef __bf16 bf16x4 __attribute__((ext_vector_type(4)));
typedef float f32x4 __attribute__((ext_vector_type(4)));

#define AS1 __attribute__((address_space(1)))
#define AS3 __attribute__((address_space(3)))

__device__ __forceinline__ void gload_lds16(const void* g, void* l) {
  __builtin_amdgcn_global_load_lds((const AS1 void*)g, (AS3 void*)l, 16, 0, 0);
}

__device__ __forceinline__ f32x4 mfma16(bf16x8 a, bf16x8 b, f32x4 c) {
  return __builtin_amdgcn_mfma_f32_16x16x32_bf16(a, b, c, 0, 0, 0);
}

#define S_LEN 2048
#define QSCALE 0.1803368801111144f  /* log2(e)/8 */

// ---------------- prep kernels ----------------

__global__ void k_split_x(const float* __restrict__ x, bf16* __restrict__ xh,
                          bf16* __restrict__ xl) {
  int i = blockIdx.x * 256 + threadIdx.x;
  float4 v = ((const float4*)x)[i];
  float vv[4] = {v.x, v.y, v.z, v.w};
  bf16x4 h, l;
#pragma unroll
  for (int j = 0; j < 4; j++) {
    bf16 hb = (bf16)vv[j];
    h[j] = hb;
    l[j] = (bf16)(vv[j] - (float)hb);
  }
  ((bf16x4*)xh)[i] = h;
  ((bf16x4*)xl)[i] = l;
}

__global__ void k_wt_qkv(const float* __restrict__ w, bf16* __restrict__ bth,
                         bf16* __restrict__ btl) {
  __shared__ float t[32][33];
  int n0 = blockIdx.x * 32, k0 = blockIdx.y * 32;
  int tx = threadIdx.x & 31, ty = threadIdx.x >> 5;
#pragma unroll
  for (int i = 0; i < 4; i++)
    t[ty + 8 * i][tx] = w[(size_t)(k0 + ty + 8 * i) * 3072 + n0 + tx];
  __syncthreads();
#pragma unroll
  for (int i = 0; i < 4; i++) {
    int r = ty + 8 * i;
    float v = t[tx][r];
    size_t o = (size_t)(n0 + r) * 1024 + k0 + tx;
    bf16 hb = (bf16)v;
    bth[o] = hb;
    btl[o] = (bf16)(v - (float)hb);
  }
}

__global__ void k_wt_out(const float* __restrict__ w, bf16* __restrict__ bt) {
  __shared__ float t[32][33];
  int n0 = blockIdx.x * 32, k0 = blockIdx.y * 32;
  int tx = threadIdx.x & 31, ty = threadIdx.x >> 5;
#pragma unroll
  for (int i = 0; i < 4; i++)
    t[ty + 8 * i][tx] = w[(size_t)(k0 + ty + 8 * i) * 1024 + n0 + tx];
  __syncthreads();
#pragma unroll
  for (int i = 0; i < 4; i++) {
    int r = ty + 8 * i;
    bt[(size_t)(n0 + r) * 1024 + k0 + tx] = (bf16)t[tx][r];
  }
}

// fp32 trig: arg error <= 2048*2^-24 ~ 1.2e-4 rad, negligible vs bf16
// rounding downstream.
__global__ void k_rope_tables(float* __restrict__ ct, float* __restrict__ st) {
  int i = blockIdx.x * 256 + threadIdx.x;   // 65536
  int s = i >> 5, j = i & 31;
  float invf = powf(10000.0f, -(float)j / 32.0f);
  float a = (float)s * invf;
  ct[i] = cosf(a);
  st[i] = sinf(a);
}

// ---------------- QKV GEMM ----------------
__global__ __launch_bounds__(256, 2) void k_gemm_qkv(
    const bf16* __restrict__ Ah, const bf16* __restrict__ Al,
    const bf16* __restrict__ Bh, const bf16* __restrict__ Bl,
    bf16* __restrict__ C) {
  const int K = 1024, N = 3072;
  __shared__ __align__(16) bf16 sAh[128 * 32];
  __shared__ __align__(16) bf16 sAl[128 * 32];
  __shared__ __align__(16) bf16 sBh[128 * 32];
  __shared__ __align__(16) bf16 sBl[128 * 32];
  int tid = threadIdx.x, lane = tid & 63, wid = tid >> 6;
  int m0 = blockIdx.x * 128, n0 = blockIdx.y * 128;
  int wm = wid >> 1, wn = wid & 1;

  f32x4 acc[4][4];
#pragma unroll
  for (int a = 0; a < 4; a++)
#pragma unroll
    for (int b = 0; b < 4; b++) acc[a][b] = (f32x4){0.f, 0.f, 0.f, 0.f};

  for (int k0 = 0; k0 < K; k0 += 32) {
#pragma unroll
    for (int p = 0; p < 2; p++) {
      int slot = p * 256 + tid;
      int row = slot >> 2, c16 = slot & 3;
      int cs = c16 ^ ((row >> 1) & 3);
      int ldsoff = (p * 256 + wid * 64) * 16;
      size_t ga = (size_t)(m0 + row) * K + k0 + cs * 8;
      size_t gb = (size_t)(n0 + row) * K + k0 + cs * 8;
      gload_lds16(Ah + ga, (char*)sAh + ldsoff);
      gload_lds16(Al + ga, (char*)sAl + ldsoff);
      gload_lds16(Bh + gb, (char*)sBh + ldsoff);
      gload_lds16(Bl + gb, (char*)sBl + ldsoff);
    }
    __syncthreads();

    bf16x8 fah[4], fal[4], fbh[4], fbl[4];
#pragma unroll
    for (int mf = 0; mf < 4; mf++) {
      int row = wm * 64 + mf * 16 + (lane & 15);
      int c16 = (lane >> 4) ^ ((row >> 1) & 3);
      int off = row * 64 + c16 * 16;
      fah[mf] = *(const bf16x8*)((const char*)sAh + off);
      fal[mf] = *(const bf16x8*)((const char*)sAl + off);
    }
#pragma unroll
    for (int nf = 0; nf < 4; nf++) {
      int row = wn * 64 + nf * 16 + (lane & 15);
      int c16 = (lane >> 4) ^ ((row >> 1) & 3);
      int off = row * 64 + c16 * 16;
      fbh[nf] = *(const bf16x8*)((const char*)sBh + off);
      fbl[nf] = *(const bf16x8*)((const char*)sBl + off);
    }
#pragma unroll
    for (int mf = 0; mf < 4; mf++)
#pragma unroll
      for (int nf = 0; nf < 4; nf++) {
        acc[mf][nf] = mfma16(fah[mf], fbh[nf], acc[mf][nf]);
        acc[mf][nf] = mfma16(fah[mf], fbl[nf], acc[mf][nf]);
        acc[mf][nf] = mfma16(fal[mf], fbh[nf], acc[mf][nf]);
      }
    __syncthreads();
  }

#pragma unroll
  for (int mf = 0; mf < 4; mf++)
#pragma unroll
    for (int nf = 0; nf < 4; nf++)
#pragma unroll
      for (int r = 0; r < 4; r++) {
        int row = m0 + wm * 64 + mf * 16 + (lane >> 4) * 4 + r;
        int col = n0 + wn * 64 + nf * 16 + (lane & 15);
        C[(size_t)row * N + col] = (bf16)acc[mf][nf][r];
      }
}

// ---------------- RoPE + scatter (Q pre-scaled by log2e/8) ----------------
__global__ void k_rope_scatter(const bf16* __restrict__ QKV,
                               const float* __restrict__ ct,
                               const float* __restrict__ st,
                               bf16* __restrict__ Q, bf16* __restrict__ Kb,
                               bf16* __restrict__ Vt) {
  __shared__ __align__(16) bf16 vt[64 * 64];
  int sblk = blockIdx.x, bh = blockIdx.y;
  int b = bh >> 4, h = bh & 15;
  int tid = threadIdx.x;
  int r = tid >> 2, c = tid & 3;
  int s = sblk * 64 + r;
  size_t rowbase = ((size_t)(b * S_LEN + s)) * 3072 + h * 192;

  bf16x8 qlo = *(const bf16x8*)(QKV + rowbase + c * 8);
  bf16x8 qhi = *(const bf16x8*)(QKV + rowbase + c * 8 + 32);
  bf16x8 klo = *(const bf16x8*)(QKV + rowbase + 64 + c * 8);
  bf16x8 khi = *(const bf16x8*)(QKV + rowbase + 64 + c * 8 + 32);
  bf16x8 vlo = *(const bf16x8*)(QKV + rowbase + 128 + c * 8);
  bf16x8 vhi = *(const bf16x8*)(QKV + rowbase + 128 + c * 8 + 32);

  bf16x8 qol, qoh, kol, koh;
#pragma unroll
  for (int j = 0; j < 8; j++) {
    float cs = ct[s * 32 + c * 8 + j], sn = st[s * 32 + c * 8 + j];
    float q1 = (float)qlo[j], q2 = (float)qhi[j];
    qol[j] = (bf16)((q1 * cs - q2 * sn) * QSCALE);
    qoh[j] = (bf16)((q2 * cs + q1 * sn) * QSCALE);
    float k1 = (float)klo[j], k2 = (float)khi[j];
    kol[j] = (bf16)(k1 * cs - k2 * sn);
    koh[j] = (bf16)(k2 * cs + k1 * sn);
  }
  size_t qb = ((size_t)bh * S_LEN + s) * 64 + c * 8;
  *(bf16x8*)(Q + qb) = qol;
  *(bf16x8*)(Q + qb + 32) = qoh;
  *(bf16x8*)(Kb + qb) = kol;
  *(bf16x8*)(Kb + qb + 32) = koh;

#pragma unroll
  for (int j = 0; j < 8; j++) {
    vt[(c * 8 + j) * 64 + r] = vlo[j];
    vt[(c * 8 + 32 + j) * 64 + r] = vhi[j];
  }
  __syncthreads();
  int d = tid >> 2, cc = tid & 3;
  size_t vb = ((size_t)bh * 64 + d) * S_LEN + sblk * 64 + cc * 16;
  *(bf16x8*)(Vt + vb) = *(const bf16x8*)(vt + d * 64 + cc * 16);
  *(bf16x8*)(Vt + vb + 8) = *(const bf16x8*)(vt + d * 64 + cc * 16 + 8);
}

// ---------------- Flash attention ----------------
// 256 thr = 4 waves; wave w owns 32 q-rows (qt*128 + w*32 + mf*16 + q).
// Grid dim3(32 bh fast, 16 qt) = 512 blocks (R9-proven; R10 showed halving
// QBLK doubles staging chip-wide -> net loss).
// K AND V double-buffered in LDS (4x16KB=64KB) -> ONE barrier per kt
// (R9 had 2; barrier drains were part of the 28% stall).
// All loop-invariant addressing hoisted out of the kt loop into registers
// (R10's VGPR=68 showed the compiler rematerializes addr math per kt).
// K staged via global_load_lds; V reg-staged (T14): global->reg at kt
// start (hidden under MFMA), reg->ds_write to the OTHER buffer pre-barrier.
// Swapped-operand S^T = mfma(K,Q) (exp2 domain), in-register P with k-slot
// permutation tau(g,j)=16*(j>>2)+4g+(j&3) applied to BOTH PV operands.
// lb(256,2): cap 256, no forced spills (R6/R7 lesson).
__global__ __launch_bounds__(256, 2) void k_attn(
    const bf16* __restrict__ Q, const bf16* __restrict__ Kb,
    const bf16* __restrict__ Vt, const int* __restrict__ mask,
    bf16* __restrict__ Ctx) {
  __shared__ __align__(16) char sKV[65536];   // [0,32K): K dbuf; [32K,64K): V dbuf
  char* sKbase = sKV;
  char* sVbase = sKV + 32768;
  int tid = threadIdx.x, lane = tid & 63, w = tid >> 6;
  int g = lane >> 4, q = lane & 15;
  int bh = blockIdx.x, qt = blockIdx.y;   // bh fast-varying: XCD/L2 locality
  int b = bh >> 4, h = bh & 15;
  int q0 = qt * 128 + w * 32;

  // Q as B-operand (pre-scaled by log2e/8 upstream)
  bf16x8 bQ[2][2];
#pragma unroll
  for (int mf = 0; mf < 2; mf++)
#pragma unroll
    for (int ks = 0; ks < 2; ks++)
      bQ[mf][ks] = *(const bf16x8*)(Q + ((size_t)bh * S_LEN + q0 + mf * 16 + q) * 64 +
                                    ks * 32 + g * 8);

  f32x4 O[2][4];
  float mrow[2], lrow[2];
#pragma unroll
  for (int mf = 0; mf < 2; mf++) {
#pragma unroll
    for (int nd = 0; nd < 4; nd++) O[mf][nd] = (f32x4){0.f, 0.f, 0.f, 0.f};
    mrow[mf] = -3e38f;
    lrow[mf] = 0.f;
  }

  // hoisted whole-row mask check
  bool rowall;
  {
    int acc = -1;
    const int4* mr = (const int4*)(mask + (size_t)b * S_LEN) + lane * 8;
#pragma unroll
    for (int p = 0; p < 8; p++) {
      int4 m4 = mr[p];
      acc &= m4.x & m4.y & m4.z & m4.w;
    }
    rowall = __all(acc != 0);
  }

  const bf16* kbase = Kb + (size_t)bh * S_LEN * 64;
  const bf16* vbase = Vt + (size_t)bh * 64 * S_LEN;

  // ---- hoisted loop-invariant addressing ----
  const bf16* kgp[4];   // K global ptr per p (starts at tile 1, += 8192/kt)
  const bf16* vgp[4];   // V global ptr per p (starts at tile 1, += 128/kt)
  int kldo[4], vldo[4]; // LDS staging dests (within-buffer, constant)
#pragma unroll
  for (int p = 0; p < 4; p++) {
    int slot = p * 256 + tid;
    int krow = slot >> 3, kc = slot & 7;
    int kcs = kc ^ (krow & 7);
    kgp[p] = kbase + (size_t)(128 + krow) * 64 + kcs * 8;
    kldo[p] = (p * 256 + w * 64) * 16;
    int vrow = slot >> 4, vc = slot & 15;
    int vcs = vc ^ (vrow & 7);
    vgp[p] = vbase + (size_t)vrow * S_LEN + 128 + vcs * 8;
    vldo[p] = (p * 256 + tid) * 16;
  }
  int koff[8][2];   // QK fragment LDS byte offsets
#pragma unroll
  for (int kf = 0; kf < 8; kf++)
#pragma unroll
    for (int ks = 0; ks < 2; ks++) {
      int row = kf * 16 + q;
      koff[kf][ks] = row * 128 + (((ks * 4 + g) ^ (row & 7)) << 4);
    }
  int voff[4][4][2];  // PV fragment LDS byte offsets
#pragma unroll
  for (int ks = 0; ks < 4; ks++)
#pragma unroll
    for (int nd = 0; nd < 4; nd++) {
      int row = nd * 16 + q;
      int u1 = (ks * 4 + (g >> 1)) ^ (row & 7);
      int u2 = (ks * 4 + (g >> 1) + 2) ^ (row & 7);
      voff[ks][nd][0] = row * 256 + ((g & 1) << 3) + (u1 << 4);
      voff[ks][nd][1] = row * 256 + ((g & 1) << 3) + (u2 << 4);
    }

  // ---- prologue: stage tile 0 ----
#pragma unroll
  for (int p = 0; p < 4; p++) {
    int slot = p * 256 + tid;
    int row = slot >> 3, c16 = slot & 7;
    int cs = c16 ^ (row & 7);
    gload_lds16(kbase + (size_t)row * 64 + cs * 8, sKbase + kldo[p]);
  }
  bf16x8 vst[4];
#pragma unroll
  for (int p = 0; p < 4; p++) {
    int slot = p * 256 + tid;
    int row = slot >> 4, c16 = slot & 15;
    int cs = c16 ^ (row & 7);
    vst[p] = *(const bf16x8*)(vbase + (size_t)row * S_LEN + cs * 8);
  }
#pragma unroll
  for (int p = 0; p < 4; p++)
    *(bf16x8*)(sVbase + vldo[p]) = vst[p];
  __syncthreads();

  int db = 0;
  for (int kt = 0; kt < 16; kt++) {
    if (kt < 15) {
      char* kdst = sKbase + (db ^ 1) * 16384;
#pragma unroll
      for (int p = 0; p < 4; p++) {
        gload_lds16(kgp[p], kdst + kldo[p]);
        kgp[p] += 128 * 64;
      }
#pragma unroll
      for (int p = 0; p < 4; p++) {
        vst[p] = *(const bf16x8*)vgp[p];
        vgp[p] += 128;
      }
    }
    const char* kl = sKbase + db * 16384;
    const char* vl = sVbase + db * 16384;

    // S^T = K Q^T
    f32x4 sfr[2][8];
#pragma unroll
    for (int mf = 0; mf < 2; mf++)
#pragma unroll
      for (int kf = 0; kf < 8; kf++) sfr[mf][kf] = (f32x4){0.f, 0.f, 0.f, 0.f};
#pragma unroll
    for (int kf = 0; kf < 8; kf++) {
#pragma unroll
      for (int ks = 0; ks < 2; ks++) {
        bf16x8 ak = *(const bf16x8*)(kl + koff[kf][ks]);
        sfr[0][kf] = mfma16(ak, bQ[0][ks], sfr[0][kf]);
        sfr[1][kf] = mfma16(ak, bQ[1][ks], sfr[1][kf]);
      }
    }
    // mask slow path (uniform; bench mask all ones)
    if (!rowall) {
      int k0 = kt * 128;
#pragma unroll
      for (int kf = 0; kf < 8; kf++) {
        int4 m4 = *(const int4*)(mask + b * S_LEN + k0 + kf * 16 + g * 4);
        int mm[4] = {m4.x, m4.y, m4.z, m4.w};
#pragma unroll
        for (int r = 0; r < 4; r++)
          if (mm[r] == 0) { sfr[0][kf][r] = -1e30f; sfr[1][kf][r] = -1e30f; }
      }
    }
    // online softmax in exp2 domain, defer-max THR=8
#pragma unroll
    for (int mf = 0; mf < 2; mf++) {
      float mx = -3e38f;
#pragma unroll
      for (int kf = 0; kf < 8; kf++)
#pragma unroll
        for (int r = 0; r < 4; r++) mx = fmaxf(mx, sfr[mf][kf][r]);
      mx = fmaxf(mx, __shfl_xor(mx, 16, 64));
      mx = fmaxf(mx, __shfl_xor(mx, 32, 64));
      if (__any(mx > mrow[mf] + 8.0f)) {
        float mnew = fmaxf(mrow[mf], mx);
        float al = exp2f(mrow[mf] - mnew);
        mrow[mf] = mnew;
        lrow[mf] *= al;
#pragma unroll
        for (int nd = 0; nd < 4; nd++)
#pragma unroll
          for (int r = 0; r < 4; r++) O[mf][nd][r] *= al;
      }
      float ps = 0.f;
#pragma unroll
      for (int kf = 0; kf < 8; kf++)
#pragma unroll
        for (int r = 0; r < 4; r++) {
          float p0 = exp2f(sfr[mf][kf][r] - mrow[mf]);
          sfr[mf][kf][r] = p0;
          ps += p0;
        }
      ps += __shfl_xor(ps, 16, 64);
      ps += __shfl_xor(ps, 32, 64);
      lrow[mf] += ps;
    }

    // PV: P^T from own registers; V from vl with MATCHING tau permutation
#pragma unroll
    for (int ks = 0; ks < 4; ks++) {
      bf16x8 pb[2];
#pragma unroll
      for (int mf = 0; mf < 2; mf++)
#pragma unroll
        for (int j = 0; j < 8; j++)
          pb[mf][j] = (bf16)sfr[mf][2 * ks + (j >> 2)][j & 3];
#pragma unroll
      for (int nd = 0; nd < 4; nd++) {
        bf16x4 v0 = *(const bf16x4*)(vl + voff[ks][nd][0]);
        bf16x4 v1 = *(const bf16x4*)(vl + voff[ks][nd][1]);
        bf16x8 av;
#pragma unroll
        for (int j = 0; j < 4; j++) { av[j] = v0[j]; av[4 + j] = v1[j]; }
        O[0][nd] = mfma16(av, pb[0], O[0][nd]);
        O[1][nd] = mfma16(av, pb[1], O[1][nd]);
      }
    }
    // write V[kt+1] into the OTHER buffer (no read hazard), then ONE barrier
    if (kt < 15) {
      char* vdst = sVbase + (db ^ 1) * 16384;
#pragma unroll
      for (int p = 0; p < 4; p++)
        *(bf16x8*)(vdst + vldo[p]) = vst[p];
    }
    __syncthreads();   // drains K gload_lds + makes V[kt+1] visible
    db ^= 1;
  }

#pragma unroll
  for (int mf = 0; mf < 2; mf++) {
    float inv = 1.f / lrow[mf];
    int srow = q0 + mf * 16 + q;
#pragma unroll
    for (int nd = 0; nd < 4; nd++) {
      bf16x4 o4;
#pragma unroll
      for (int r = 0; r < 4; r++) o4[r] = (bf16)(O[mf][nd][r] * inv);
      *(bf16x4*)(Ctx + ((size_t)b * S_LEN + srow) * 1024 + h * 64 + nd * 16 + g * 4) = o4;
    }
  }
}

// ---------------- out GEMM ----------------
__global__ __launch_bounds__(256, 2) void k_gemm_out(
    const bf16* __restrict__ A, const bf16* __restrict__ Bt,
    float* __restrict__ C) {
  const int K = 1024, N = 1024;
  __shared__ __align__(16) bf16 sA[128 * 32];
  __shared__ __align__(16) bf16 sB[128 * 32];
  int tid = threadIdx.x, lane = tid & 63, wid = tid >> 6;
  int m0 = blockIdx.x * 128, n0 = blockIdx.y * 128;
  int wm = wid >> 1, wn = wid & 1;

  f32x4 acc[4][4];
#pragma unroll
  for (int a = 0; a < 4; a++)
#pragma unroll
    for (int b = 0; b < 4; b++) acc[a][b] = (f32x4){0.f, 0.f, 0.f, 0.f};

  for (int k0 = 0; k0 < K; k0 += 32) {
#pragma unroll
    for (int p = 0; p < 2; p++) {
      int slot = p * 256 + tid;
      int row = slot >> 2, c16 = slot & 3;
      int cs = c16 ^ ((row >> 1) & 3);
      int ldsoff = (p * 256 + wid * 64) * 16;
      gload_lds16(A + (size_t)(m0 + row) * K + k0 + cs * 8, (char*)sA + ldsoff);
      gload_lds16(Bt + (size_t)(n0 + row) * K + k0 + cs * 8, (char*)sB + ldsoff);
    }
    __syncthreads();
    bf16x8 fa[4], fb[4];
#pragma unroll
    for (int mf = 0; mf < 4; mf++) {
      int row = wm * 64 + mf * 16 + (lane & 15);
      int c16 = (lane >> 4) ^ ((row >> 1) & 3);
      fa[mf] = *(const bf16x8*)((const char*)sA + row * 64 + c16 * 16);
    }
#pragma unroll
    for (int nf = 0; nf < 4; nf++) {
      int row = wn * 64 + nf * 16 + (lane & 15);
      int c16 = (lane >> 4) ^ ((row >> 1) & 3);
      fb[nf] = *(const bf16x8*)((const char*)sB + row * 64 + c16 * 16);
    }
#pragma unroll
    for (int mf = 0; mf < 4; mf++)
#pragma unroll
      for (int nf = 0; nf < 4; nf++)
        acc[mf][nf] = mfma16(fa[mf], fb[nf], acc[mf][nf]);
    __syncthreads();
  }
#pragma unroll
  for (int mf = 0; mf < 4; mf++)
#pragma unroll
    for (int nf = 0; nf < 4; nf++)
#pragma unroll
      for (int r = 0; r < 4; r++) {
        int row = m0 + wm * 64 + mf * 16 + (lane >> 4) * 4 + r;
        int col = n0 + wn * 64 + nf * 16 + (lane & 15);
        C[(size_t)row * N + col] = acc[mf][nf][r];
      }
}

// ---------------- launch ----------------
extern "C" void kernel_launch(void* const* d_in, const int* in_sizes, int n_in,
                              void* d_out, int out_size, void* d_ws, size_t ws_size,
                              hipStream_t stream) {
  const float* x = (const float*)d_in[0];
  const int* mask = (const int*)d_in[1];
  const float* wqkv = (const float*)d_in[2];
  const float* wout = (const float*)d_in[3];
  float* out = (float*)d_out;
  char* ws = (char*)d_ws;

  bf16* Xh  = (bf16*)(ws + 0);
  bf16* Xl  = (bf16*)(ws + 8388608);
  bf16* Wqh = (bf16*)(ws + 16777216);
  bf16* Wql = (bf16*)(ws + 23068672);
  bf16* Wo  = (bf16*)(ws + 29360128);
  bf16* QKV = (bf16*)(ws + 31457280);
  bf16* Qb  = (bf16*)(ws + 56623104);
  bf16* Kb  = (bf16*)(ws + 65011712);
  bf16* Vt  = (bf16*)(ws + 73400320);
  bf16* Ctx = (bf16*)(ws + 81788928);
  float* ct = (float*)(ws + 90177536);
  float* st = (float*)(ws + 90439680);

  k_split_x<<<4096, 256, 0, stream>>>(x, Xh, Xl);
  k_wt_qkv<<<dim3(96, 32), 256, 0, stream>>>(wqkv, Wqh, Wql);
  k_wt_out<<<dim3(32, 32), 256, 0, stream>>>(wout, Wo);
  k_rope_tables<<<256, 256, 0, stream>>>(ct, st);
  k_gemm_qkv<<<dim3(32, 24), 256, 0, stream>>>(Xh, Xl, Wqh, Wql, QKV);
  k_rope_scatter<<<dim3(32, 32), 256, 0, stream>>>(QKV, ct, st, Qb, Kb, Vt);
  k_attn<<<dim3(32, 16), 256, 0, stream>>>(Qb, Kb, Vt, mask, Ctx);
  k_gemm_out<<<dim3(32, 8), 256, 0, stream>>>(Ctx, Wo, out);
}